// Round 2
// baseline (232.565 us; speedup 1.0000x reference)
//
#include <hip/hip_runtime.h>
#include <math.h>

// GatingNetwork R8: R7 structure + R6's proven RNE split3 (numerics fix).
//   logits = x[16384,2048] @ W[2048,64] + b; softmax; top-2.
//   Out (fp32 flat): topk_w[T,2] | topk_idx[T,2] (float) | weights[T,E].
//
// R7 post-mortem: structure audit clean (layouts/pipeline/bounds all match
// R6-proven mappings), but truncation split has 2^-7 residual bounds (vs
// RNE 2^-8), putting dropped m*l cross terms at ~1e-6 logit error -> 1-2
// near-tie top-2 index flips over 16K tokens (output0 passed, output1
// absmax 26 = flipped index). R5 showed the same mode at 1e-5. R6's RNE
// split (~1e-7) passed with zero flips. R8 restores RNE split everywhere;
// per-logit MFMA term sequence/k-order now identical to R6.
//
// Structure (unchanged from R7):
//  * wconv_kernel (once, ~3us): RNE 3-way bf16 split of W into d_ws as
//    MFMA-B-fragment-ready planes. frag(ks,nt,p) = 1KB contiguous; lane l
//    elem j = W[ks*32+(l>>4)*8+j][nt*16+(l&15)] (B[k][n], m89/m120).
//    ws_size >= 786432 B required.
//  * gating_kernel: 1024 blocks x 64 thr (1 wave; grid = exactly 1 wave per
//    SIMD device-wide). Wave owns 16 tokens, all 64 experts, acc[4] f32x4.
//    NO __syncthreads in main loop. A-frags split in registers; B-frags
//    direct dwordx4 from pre-swizzled planes (L1-shared across the CU's 4
//    lockstep waves), double-buffered 2 ksteps ahead; x prefetch distance 4.
//    24 MFMA 16x16x32_bf16 per kstep (6 exact-split terms x 4 n-tiles).
//  * Epilogue: lg[16][65] in LDS; 4-lanes-per-row softmax/top-2 with
//    shfl_xor merge (strict > , tie -> lower index = jax top_k).
//
// Predictions: passes (absmax ~1e-3); main dispatch ~30us (x HBM floor
// 21us, B L2 stream overlapped); bank conflicts ~0; VALUBusy 40-55%;
// MfmaUtil ~20%; Occupancy ~12% by design.

#define T_TOK 16384
#define DMOD  2048
#define NEXP  64
#define NKS   64   // DMOD / 32 ksteps

typedef __attribute__((ext_vector_type(8))) short short8;
typedef __attribute__((ext_vector_type(4))) float f32x4;

#define MFMA16 __builtin_amdgcn_mfma_f32_16x16x32_bf16

__device__ __forceinline__ unsigned short bf16_rne(float f) {
  unsigned int u = __float_as_uint(f);
  unsigned int r = (u + 0x7fffu + ((u >> 16) & 1u)) >> 16;
  return (unsigned short)r;
}
__device__ __forceinline__ float bf16_up(unsigned short h) {
  return __uint_as_float(((unsigned int)h) << 16);
}

// Exact-to-2^-27 RNE 3-way bf16 split of a pair, packed little-endian
// (elem0 -> low 16). Same numerics as R6 (proven: absmax 9.8e-4, 0 flips).
__device__ __forceinline__ void split3_pair(float v0, float v1, unsigned& hp,
                                            unsigned& mp, unsigned& lp) {
  const unsigned short h0 = bf16_rne(v0), h1 = bf16_rne(v1);
  const float e0 = v0 - bf16_up(h0), e1 = v1 - bf16_up(h1);
  const unsigned short m0 = bf16_rne(e0), m1 = bf16_rne(e1);
  const float g0 = e0 - bf16_up(m0), g1 = e1 - bf16_up(m1);
  const unsigned short l0 = bf16_rne(g0), l1 = bf16_rne(g1);
  hp = (unsigned)h0 | ((unsigned)h1 << 16);
  mp = (unsigned)m0 | ((unsigned)m1 << 16);
  lp = (unsigned)l0 | ((unsigned)l1 << 16);
}

__global__ __launch_bounds__(256) void wconv_kernel(
    const float* __restrict__ W, unsigned short* __restrict__ wp) {
  const int tid = blockIdx.x * 256 + threadIdx.x;  // 0..16383
  const int l = tid & 63;
  const int g = tid >> 6;            // g = ks*4 + nt, 0..255
  const int q = l >> 4, c = l & 15;
  const int ks = g >> 2, nt = g & 3;
  const int k0 = ks * 32 + q * 8;
  const int n = nt * 16 + c;
  float v[8];
#pragma unroll
  for (int j = 0; j < 8; ++j) v[j] = W[(size_t)(k0 + j) * NEXP + n];
  uint4 h, m, lo;
  split3_pair(v[0], v[1], h.x, m.x, lo.x);
  split3_pair(v[2], v[3], h.y, m.y, lo.y);
  split3_pair(v[4], v[5], h.z, m.z, lo.z);
  split3_pair(v[6], v[7], h.w, m.w, lo.w);
  // frag(ks,nt,p) at ((g*3 + p)*512 + l*8) shorts
  unsigned short* base = wp + (size_t)g * 1536 + l * 8;
  *(uint4*)(base) = h;
  *(uint4*)(base + 512) = m;
  *(uint4*)(base + 1024) = lo;
}

__global__ __launch_bounds__(64) void gating_kernel(
    const float* __restrict__ x, const unsigned short* __restrict__ wp,
    const float* __restrict__ bias, float* __restrict__ out) {
  __shared__ float lg[16 * 65];
  __shared__ float red_m[16];
  __shared__ float red_s[16];

  const int l = threadIdx.x;  // 0..63
  const int q = l >> 4, c = l & 15;
  const int t0 = blockIdx.x * 16;

  const float* xg = x + (size_t)(t0 + c) * DMOD + q * 8;
  const unsigned short* wl = wp + l * 8;

  float bv[4];
#pragma unroll
  for (int nt = 0; nt < 4; ++nt) bv[nt] = bias[nt * 16 + c];

  f32x4 acc[4];
#pragma unroll
  for (int nt = 0; nt < 4; ++nt) acc[nt] = (f32x4){0.f, 0.f, 0.f, 0.f};

  float4 xr[4][2];   // raw x for kstep == i (mod 4); prefetch distance 4
  short8 bb[2][12];  // B frags, double-buffered (distance 2)

  // prologue
#pragma unroll
  for (int i = 0; i < 4; ++i) {
    xr[i][0] = *(const float4*)(xg + i * 32);
    xr[i][1] = *(const float4*)(xg + i * 32 + 4);
  }
#pragma unroll
  for (int i = 0; i < 12; ++i) {
    bb[0][i] = *(const short8*)(wl + (size_t)i * 512);
    bb[1][i] = *(const short8*)(wl + (size_t)(12 + i) * 512);
  }

  for (int blk = 0; blk < 16; ++blk) {
#pragma unroll
    for (int u = 0; u < 4; ++u) {
      const int ks = blk * 4 + u;
      // convert current x (registers only)
      short8 ah, am, al;
      {
        uint4 h, m, lo;
        split3_pair(xr[u][0].x, xr[u][0].y, h.x, m.x, lo.x);
        split3_pair(xr[u][0].z, xr[u][0].w, h.y, m.y, lo.y);
        split3_pair(xr[u][1].x, xr[u][1].y, h.z, m.z, lo.z);
        split3_pair(xr[u][1].z, xr[u][1].w, h.w, m.w, lo.w);
        ah = *(short8*)&h;
        am = *(short8*)&m;
        al = *(short8*)&lo;
      }
      // refill this x slot for ks+4 (clamped tail reads are harmless)
      {
        const int kn = (ks + 4 < NKS) ? ks + 4 : NKS - 1;
        xr[u][0] = *(const float4*)(xg + kn * 32);
        xr[u][1] = *(const float4*)(xg + kn * 32 + 4);
      }
      // 6 exact-split terms x 4 n-tiles
      const int pb = u & 1;
#pragma unroll
      for (int nt = 0; nt < 4; ++nt) {
        const short8 bh = bb[pb][nt * 3 + 0];
        const short8 bm = bb[pb][nt * 3 + 1];
        const short8 bl = bb[pb][nt * 3 + 2];
        acc[nt] = MFMA16(ah, bh, acc[nt], 0, 0, 0);
        acc[nt] = MFMA16(ah, bm, acc[nt], 0, 0, 0);
        acc[nt] = MFMA16(am, bh, acc[nt], 0, 0, 0);
        acc[nt] = MFMA16(am, bm, acc[nt], 0, 0, 0);
        acc[nt] = MFMA16(ah, bl, acc[nt], 0, 0, 0);
        acc[nt] = MFMA16(al, bh, acc[nt], 0, 0, 0);
      }
      // refill this B buffer for ks+2 (after MFMAs consumed it)
      {
        const int kn = (ks + 2 < NKS) ? ks + 2 : NKS - 1;
        const unsigned short* src = wl + (size_t)kn * 6144;
#pragma unroll
        for (int i = 0; i < 12; ++i)
          bb[pb][i] = *(const short8*)(src + (size_t)i * 512);
      }
    }
  }

  // ---- logits -> LDS (D: col=l&15 -> expert nt*16+c, row=q*4+r -> token) ----
#pragma unroll
  for (int nt = 0; nt < 4; ++nt)
#pragma unroll
    for (int r = 0; r < 4; ++r)
      lg[(q * 4 + r) * 65 + nt * 16 + c] = acc[nt][r] + bv[nt];
  __syncthreads();

  // ---- wave-parallel softmax + top-2: 4 lanes per token row ----
  {
    const int row = l >> 2;  // 0..15
    const int s = l & 3;     // 0..3: experts s*16 .. s*16+15
    const float* lr = lg + row * 65 + s * 16;
    float mx = -INFINITY;
#pragma unroll
    for (int e = 0; e < 16; ++e) mx = fmaxf(mx, lr[e]);
    mx = fmaxf(mx, __shfl_xor(mx, 1));
    mx = fmaxf(mx, __shfl_xor(mx, 2));
    float sum = 0.f, b1 = -INFINITY, b2 = -INFINITY;
    int i1 = 0, i2 = 0;
#pragma unroll
    for (int e = 0; e < 16; ++e) {
      const float v = lr[e];
      sum += expf(v - mx);
      const int idx = s * 16 + e;
      if (v > b1) {  // strict >: ties keep lowest index (jax top_k)
        b2 = b1; i2 = i1; b1 = v; i1 = idx;
      } else if (v > b2) {
        b2 = v; i2 = idx;
      }
    }
#pragma unroll
    for (int msk = 1; msk <= 2; msk <<= 1) {
      sum += __shfl_xor(sum, msk);
      const float ob1 = __shfl_xor(b1, msk);
      const int oi1 = __shfl_xor(i1, msk);
      const float ob2 = __shfl_xor(b2, msk);
      const int oi2 = __shfl_xor(i2, msk);
      float n1, n2;
      int j1, j2;
      const bool aFirst = (b1 > ob1) || (b1 == ob1 && i1 < oi1);
      if (aFirst) {
        n1 = b1; j1 = i1;
        const bool t = (b2 > ob1) || (b2 == ob1 && i2 < oi1);
        n2 = t ? b2 : ob1; j2 = t ? i2 : oi1;
      } else {
        n1 = ob1; j1 = oi1;
        const bool t = (ob2 > b1) || (ob2 == b1 && oi2 < i1);
        n2 = t ? ob2 : b1; j2 = t ? oi2 : i1;
      }
      b1 = n1; i1 = j1; b2 = n2; i2 = j2;
    }
    if (s == 0) {
      const float inv = 1.f / sum;
      const int t = t0 + row;
      float2 wv, iv;
      wv.x = expf(b1 - mx) * inv;
      wv.y = expf(b2 - mx) * inv;
      iv.x = (float)i1;
      iv.y = (float)i2;
      *(float2*)(out + 2 * t) = wv;
      *(float2*)(out + 2 * T_TOK + 2 * t) = iv;
      red_m[row] = mx;
      red_s[row] = inv;
    }
  }
  __syncthreads();

  // ---- full softmax weights, coalesced (one token row per iteration) ----
#pragma unroll
  for (int it = 0; it < 16; ++it) {
    out[4 * T_TOK + (size_t)(t0 + it) * NEXP + l] =
        expf(lg[it * 65 + l] - red_m[it]) * red_s[it];
  }
}

extern "C" void kernel_launch(void* const* d_in, const int* in_sizes, int n_in,
                              void* d_out, int out_size, void* d_ws,
                              size_t ws_size, hipStream_t stream) {
  const float* x = (const float*)d_in[0];
  const float* W = (const float*)d_in[1];
  const float* b = (const float*)d_in[2];
  float* out = (float*)d_out;
  unsigned short* wp = (unsigned short*)d_ws;  // needs 786432 B
  wconv_kernel<<<dim3(64), dim3(256), 0, stream>>>(W, wp);
  gating_kernel<<<dim3(T_TOK / 16), dim3(64), 0, stream>>>(x, wp, b, out);
}